// Round 5
// baseline (112.631 us; speedup 1.0000x reference)
//
#include <hip/hip_runtime.h>
#include <hip/hip_bf16.h>

constexpr int B = 8, N = 2048, FIN = 128, FOUT = 64;

typedef __attribute__((ext_vector_type(8))) short short8;
typedef __attribute__((ext_vector_type(4))) float f32x4;

// round-to-nearest-even f32 -> bf16 bits (finite inputs only)
__device__ __forceinline__ unsigned short f2bf(float f) {
    unsigned int x = __float_as_uint(f);
    return (unsigned short)((x + 0x7fffu + ((x >> 16) & 1u)) >> 16);
}

// ---------------- K1: h = input @ W (bf16, row-major) ; s1 ; s2 ------------
__global__ __launch_bounds__(256) void k1_h(
        const float* __restrict__ inp, const float* __restrict__ W,
        const float* __restrict__ a, unsigned short* __restrict__ h,
        float* __restrict__ s1, float* __restrict__ s2) {
    int wave = threadIdx.x >> 6;
    int lane = threadIdx.x & 63;
    int row  = blockIdx.x * 4 + wave;            // [0, B*N)
    const float* irow = inp + (size_t)row * FIN;
    float acc = 0.f;
    #pragma unroll 16
    for (int k = 0; k < FIN; ++k)
        acc = fmaf(irow[k], W[k * FOUT + lane], acc);
    h[(size_t)row * FOUT + lane] = f2bf(acc);
    float p1 = acc * a[lane];
    float p2 = acc * a[FOUT + lane];
    #pragma unroll
    for (int off = 32; off > 0; off >>= 1) {
        p1 += __shfl_down(p1, off);
        p2 += __shfl_down(p2, off);
    }
    if (lane == 0) { s1[row] = p1; s2[row] = p2; }
}

// ---------------- K1b: hT[b][o][i] = h[b][i][o]  (bf16 transpose) ----------
__global__ __launch_bounds__(256) void k1b_t(
        const unsigned short* __restrict__ h, unsigned short* __restrict__ hT) {
    __shared__ unsigned short tile[64][72];
    int b = blockIdx.y, i0 = blockIdx.x * 64;
    int t = threadIdx.x;
    int r = t >> 2, cq = t & 3;
    const unsigned short* src = h + ((size_t)b * N + i0 + r) * FOUT + cq * 16;
    *(short8*)&tile[r][cq * 16]     = *(const short8*)src;
    *(short8*)&tile[r][cq * 16 + 8] = *(const short8*)(src + 8);
    __syncthreads();
    int o = t >> 2, iq = t & 3;
    union { short8 s8; unsigned short u[8]; } w0, w1;
    #pragma unroll
    for (int e = 0; e < 8; ++e) {
        w0.u[e] = tile[iq * 16 + e][o];
        w1.u[e] = tile[iq * 16 + 8 + e][o];
    }
    unsigned short* dst = hT + ((size_t)b * FOUT + o) * N + i0 + iq * 16;
    *(short8*)dst       = w0.s8;
    *(short8*)(dst + 8) = w1.s8;
}

// ---- K2a: PV MFMA on unnormalized e~ + per-row expsum -> rv, out ----------
// 512 thr / 8 waves; 16 rows/block; 8-way K-split (wave kc owns 256 cols).
// No max-subtraction (logits |x| <~ 7 -> exp safe in f32/bf16).
__global__ __launch_bounds__(512, 8) void k2a_pv(
        const float* __restrict__ s1g, const float* __restrict__ s2g,
        const int* __restrict__ adj, const unsigned short* __restrict__ hT,
        float* __restrict__ rvg, float* __restrict__ out) {
    __shared__ float s2l[N];                 // 8 KB
    __shared__ float s1l[16];
    __shared__ float ps[8][16];              // per-K-chunk row expsum
    __shared__ float rvl[16];
    __shared__ float red[7][16][68];         // 29.75 KB C-partial reduce

    int b = blockIdx.y, m0 = blockIdx.x * 16;
    int t = threadIdx.x, kc = t >> 6, lane = t & 63;
    int r = lane & 15, g = lane >> 4;

    for (int j = t; j < N; j += 512) s2l[j] = s2g[(size_t)b * N + j];
    if (t < 16) s1l[t] = s1g[(size_t)b * N + m0 + t];
    __syncthreads();

    float s1v = s1l[r];
    const int* arow = adj + (size_t)(m0 + r) * N;
    const unsigned short* hbase = hT + (size_t)b * FOUT * N;

    f32x4 acc[4];
    #pragma unroll
    for (int nf = 0; nf < 4; ++nf)
        #pragma unroll
        for (int q = 0; q < 4; ++q) acc[nf][q] = 0.f;
    float rsum = 0.f;

    #pragma unroll
    for (int st = 0; st < 8; ++st) {
        int jb = kc * 256 + st * 32 + g * 8;
        int4 a0 = *(const int4*)&arow[jb];
        int4 a1 = *(const int4*)&arow[jb + 4];
        float4 sA = *(const float4*)&s2l[jb];
        float4 sB = *(const float4*)&s2l[jb + 4];
        int   ai[8] = {a0.x, a0.y, a0.z, a0.w, a1.x, a1.y, a1.z, a1.w};
        float sj[8] = {sA.x, sA.y, sA.z, sA.w, sB.x, sB.y, sB.z, sB.w};
        float e8[8];
        #pragma unroll
        for (int e = 0; e < 8; ++e) {
            float x = s1v + sj[e];
            x = fmaxf(x, 0.2f * x);              // leaky_relu(0.2)
            float pe = __expf(x);
            e8[e] = (ai[e] > 0) ? pe : 0.f;      // masked -> exact 0
            rsum += e8[e];
        }
        union { short8 s8; unsigned short u[8]; } pk;
        #pragma unroll
        for (int e = 0; e < 8; ++e) pk.u[e] = f2bf(e8[e]);
        #pragma unroll
        for (int nf = 0; nf < 4; ++nf) {
            short8 Bf = *(const short8*)&hbase[(size_t)(nf * 16 + r) * N + jb];
            acc[nf] = __builtin_amdgcn_mfma_f32_16x16x32_bf16(pk.s8, Bf, acc[nf], 0, 0, 0);
        }
    }
    // reduce e~ sums across the 4 lanes sharing row r
    rsum += __shfl_xor(rsum, 16);
    rsum += __shfl_xor(rsum, 32);
    if (lane < 16) ps[kc][r] = rsum;
    if (kc > 0) {
        #pragma unroll
        for (int nf = 0; nf < 4; ++nf)
            #pragma unroll
            for (int q = 0; q < 4; ++q)
                red[kc - 1][4 * g + q][nf * 16 + r] = acc[nf][q];
    }
    __syncthreads();
    if (t < 16) {
        float sum = ps[0][t] + ps[1][t] + ps[2][t] + ps[3][t]
                  + ps[4][t] + ps[5][t] + ps[6][t] + ps[7][t];
        float rv = 1.0f / sum;
        rvl[t] = rv;
        rvg[(size_t)b * N + m0 + t] = rv;
    }
    __syncthreads();
    if (kc == 0) {
        #pragma unroll
        for (int nf = 0; nf < 4; ++nf) {
            #pragma unroll
            for (int q = 0; q < 4; ++q) {
                int m = 4 * g + q;               // C/D: row=(lane>>4)*4+reg
                int o = nf * 16 + r;             // C/D: col=lane&15
                float vv = acc[nf][q];
                #pragma unroll
                for (int z = 0; z < 7; ++z) vv += red[z][m][o];
                vv *= rvl[m];
                out[((size_t)b * N + m0 + m) * FOUT + o] = vv > 0.f ? vv : 0.f;
            }
        }
    }
}

// ---- K2b: stream att = e~ * rv; one node-row i per block, all 8 batches ---
// adj row loaded ONCE into LDS, reused by all 8 batch-rows.
__global__ __launch_bounds__(256) void k2b_att(
        const float* __restrict__ s1g, const float* __restrict__ s2g,
        const int* __restrict__ adj, const float* __restrict__ rvg,
        float* __restrict__ att) {
    __shared__ int adjl[N];                  // 8 KB
    int i = blockIdx.x;
    int t = threadIdx.x, w = t >> 6, lane = t & 63;
    const int* arow = adj + (size_t)i * N;
    {
        int j = t * 8;                        // 2048 ints / 256 thr
        *(int4*)&adjl[j]     = *(const int4*)&arow[j];
        *(int4*)&adjl[j + 4] = *(const int4*)&arow[j + 4];
    }
    __syncthreads();
    #pragma unroll
    for (int bb = 0; bb < 2; ++bb) {
        int b = w * 2 + bb;                   // wave w -> batches 2w, 2w+1
        float s1v = s1g[(size_t)b * N + i];
        float rv  = rvg[(size_t)b * N + i];
        const float* s2b = s2g + (size_t)b * N;
        float* orow = att + ((size_t)b * N + i) * N;
        #pragma unroll
        for (int it = 0; it < 8; ++it) {
            int j = it * 256 + lane * 4;      // wave writes 1KB contiguous
            int4  av = *(const int4*)&adjl[j];
            float4 sv = *(const float4*)&s2b[j];
            float x0 = s1v + sv.x; x0 = fmaxf(x0, 0.2f * x0);
            float x1 = s1v + sv.y; x1 = fmaxf(x1, 0.2f * x1);
            float x2 = s1v + sv.z; x2 = fmaxf(x2, 0.2f * x2);
            float x3 = s1v + sv.w; x3 = fmaxf(x3, 0.2f * x3);
            float4 o;
            o.x = (av.x > 0) ? __expf(x0) * rv : 0.f;
            o.y = (av.y > 0) ? __expf(x1) * rv : 0.f;
            o.z = (av.z > 0) ? __expf(x2) * rv : 0.f;
            o.w = (av.w > 0) ? __expf(x3) * rv : 0.f;
            *(float4*)&orow[j] = o;
        }
    }
}

extern "C" void kernel_launch(void* const* d_in, const int* in_sizes, int n_in,
                              void* d_out, int out_size, void* d_ws, size_t ws_size,
                              hipStream_t stream) {
    const float* inp = (const float*)d_in[0];   // (8,2048,128) f32
    const int*   adj = (const int*)d_in[1];     // (2048,2048) i32
    const float* W   = (const float*)d_in[2];   // (128,64) f32
    const float* a   = (const float*)d_in[3];   // (128,1) f32

    float* out = (float*)d_out;                        // (8,2048,64)
    float* att = out + (size_t)B * N * FOUT;           // (8,2048,2048)

    unsigned short* h  = (unsigned short*)d_ws;        // 2 MB bf16
    unsigned short* hT = h + (size_t)B * N * FOUT;     // 2 MB bf16
    float* s1  = (float*)(hT + (size_t)B * N * FOUT);  // 64 KB
    float* s2  = s1 + (size_t)B * N;                   // 64 KB
    float* rvg = s2 + (size_t)B * N;                   // 64 KB

    k1_h<<<B * N / 4, 256, 0, stream>>>(inp, W, a, h, s1, s2);
    dim3 gt(N / 64, B);
    k1b_t<<<gt, 256, 0, stream>>>(h, hT);
    dim3 g2a(N / 16, B);
    k2a_pv<<<g2a, 512, 0, stream>>>(s1, s2, adj, hT, rvg, out);
    k2b_att<<<N, 256, 0, stream>>>(s1, s2, adj, rvg, att);
}

// Round 6
// 92.034 us; speedup vs baseline: 1.2238x; 1.2238x over previous
//
#include <hip/hip_runtime.h>
#include <hip/hip_bf16.h>

constexpr int B = 8, N = 2048, FIN = 128, FOUT = 64;

typedef __attribute__((ext_vector_type(8))) short short8;
typedef __attribute__((ext_vector_type(4))) float f32x4;

// f32 pair -> packed bf16 (RNE) via v_cvt_pk_bf16_f32
__device__ __forceinline__ unsigned int pk_bf16(float lo, float hi) {
    union { __hip_bfloat162 h2; unsigned int u; } c;
    c.h2 = __float22bfloat162_rn(float2{lo, hi});
    return c.u;
}

// ---- kA: [blocks 0..255] h=inp@W -> hT (bf16), s1, s2 ; [256..511] adj->bits
__global__ __launch_bounds__(512, 4) void kA(
        const float* __restrict__ inp, const float* __restrict__ W,
        const float* __restrict__ a, const int* __restrict__ adj,
        unsigned short* __restrict__ hT, float* __restrict__ s1,
        float* __restrict__ s2, unsigned long long* __restrict__ adjbits) {
    __shared__ unsigned short tile[64][72];
    int bx = blockIdx.x, t = threadIdx.x, w = t >> 6, lane = t & 63;

    if (bx >= 256) {                              // ---- adj bit-pack ----
        int row = (bx - 256) * 8 + w;             // [0,2048)
        const int* ar = adj + (size_t)row * N;
        unsigned long long* br = adjbits + (size_t)row * 32;
        #pragma unroll 8
        for (int wq = 0; wq < 32; ++wq) {
            unsigned long long m = __ballot(ar[wq * 64 + lane] > 0);
            if (lane == 0) br[wq] = m;
        }
        return;
    }
    // ---- h tile: b, rows i0..i0+63 ----
    int b = bx >> 5, i0 = (bx & 31) * 64;
    float a1 = a[lane], a2 = a[FOUT + lane];
    const float* ib = inp + ((size_t)b * N + i0 + w * 8) * FIN;
    float acc[8] = {};
    for (int k = 0; k < FIN; ++k) {
        float wv = W[k * FOUT + lane];
        #pragma unroll
        for (int rr = 0; rr < 8; ++rr)
            acc[rr] = fmaf(ib[rr * FIN + k], wv, acc[rr]);
    }
    #pragma unroll
    for (int rr = 0; rr < 8; ++rr) {
        float p1 = acc[rr] * a1, p2 = acc[rr] * a2;
        #pragma unroll
        for (int off = 32; off > 0; off >>= 1) {
            p1 += __shfl_down(p1, off);
            p2 += __shfl_down(p2, off);
        }
        int row = i0 + w * 8 + rr;
        if (lane == 0) { s1[(size_t)b * N + row] = p1; s2[(size_t)b * N + row] = p2; }
        tile[w * 8 + rr][lane] = (unsigned short)(pk_bf16(acc[rr], 0.f) & 0xFFFF);
    }
    __syncthreads();
    int o = t >> 3, iq = t & 7;                   // transpose-write hT
    union { short8 s8; unsigned short u[8]; } tw;
    #pragma unroll
    for (int e = 0; e < 8; ++e) tw.u[e] = tile[iq * 8 + e][o];
    *(short8*)&hT[((size_t)b * FOUT + o) * N + i0 + iq * 8] = tw.s8;
}

// ---- K2a: PV MFMA on unnormalized e~ + row expsum -> rv, out --------------
// 1024 thr / 16 waves; 64 rows/block; wave: row-group s=w&3, K-chunk kc=w>>2.
__global__ __launch_bounds__(1024, 4) void k2a_pv(
        const float* __restrict__ s1g, const float* __restrict__ s2g,
        const unsigned long long* __restrict__ adjbits,
        const unsigned short* __restrict__ hT,
        float* __restrict__ rvg, float* __restrict__ out) {
    __shared__ float s2l[N];                 // 8 KB
    __shared__ float s1l[64];
    __shared__ float ps[4][64];
    __shared__ float rvl[64];
    __shared__ float red[3][64][68];         // 52.2 KB partial-C reduce

    int b = blockIdx.y, m0 = blockIdx.x * 64;
    int t = threadIdx.x, w = t >> 6, lane = t & 63;
    int s = w & 3, kc = w >> 2;
    int r = lane & 15, g = lane >> 4;

    for (int j = t; j < N; j += 1024) s2l[j] = s2g[(size_t)b * N + j];
    if (t < 64) s1l[t] = s1g[(size_t)b * N + m0 + t];
    __syncthreads();

    int lrow = s * 16 + r;
    float s1v = s1l[lrow];
    const unsigned long long* brow = adjbits + (size_t)(m0 + lrow) * 32;
    const unsigned short* hbase = hT + (size_t)b * FOUT * N;

    f32x4 acc[4];
    #pragma unroll
    for (int nf = 0; nf < 4; ++nf)
        #pragma unroll
        for (int q = 0; q < 4; ++q) acc[nf][q] = 0.f;
    float rsum = 0.f;

    #pragma unroll
    for (int st = 0; st < 16; ++st) {
        int jb = kc * 512 + st * 32 + g * 8;
        unsigned int bits = (unsigned int)(brow[jb >> 6] >> (jb & 63)) & 0xFFu;
        float4 sA = *(const float4*)&s2l[jb];
        float4 sB = *(const float4*)&s2l[jb + 4];
        float sj[8] = {sA.x, sA.y, sA.z, sA.w, sB.x, sB.y, sB.z, sB.w};
        float e8[8];
        #pragma unroll
        for (int e = 0; e < 8; ++e) {
            float x = s1v + sj[e];
            x = fmaxf(x, 0.2f * x);              // leaky_relu(0.2)
            float pe = __expf(x);                // |x| <~ 7 -> safe, no max-sub
            e8[e] = ((bits >> e) & 1u) ? pe : 0.f;
            rsum += e8[e];
        }
        union { short8 s8; unsigned int d[4]; } pk;
        #pragma unroll
        for (int e = 0; e < 4; ++e) pk.d[e] = pk_bf16(e8[2 * e], e8[2 * e + 1]);
        #pragma unroll
        for (int nf = 0; nf < 4; ++nf) {
            short8 Bf = *(const short8*)&hbase[(size_t)(nf * 16 + r) * N + jb];
            acc[nf] = __builtin_amdgcn_mfma_f32_16x16x32_bf16(pk.s8, Bf, acc[nf], 0, 0, 0);
        }
    }
    rsum += __shfl_xor(rsum, 16);
    rsum += __shfl_xor(rsum, 32);
    if (lane < 16) ps[kc][lrow] = rsum;
    if (kc > 0) {
        #pragma unroll
        for (int nf = 0; nf < 4; ++nf)
            #pragma unroll
            for (int q = 0; q < 4; ++q)
                red[kc - 1][s * 16 + 4 * g + q][nf * 16 + r] = acc[nf][q];
    }
    __syncthreads();
    if (t < 64) {
        float rv = 1.0f / (ps[0][t] + ps[1][t] + ps[2][t] + ps[3][t]);
        rvl[t] = rv;
        rvg[(size_t)b * N + m0 + t] = rv;
    }
    __syncthreads();
    if (kc == 0) {
        #pragma unroll
        for (int nf = 0; nf < 4; ++nf) {
            #pragma unroll
            for (int q = 0; q < 4; ++q) {
                int m = s * 16 + 4 * g + q;      // C/D: row=(lane>>4)*4+reg
                int o = nf * 16 + r;             // C/D: col=lane&15
                float vv = acc[nf][q] + red[0][m][o] + red[1][m][o] + red[2][m][o];
                vv *= rvl[m];
                out[((size_t)b * N + m0 + m) * FOUT + o] = vv > 0.f ? vv : 0.f;
            }
        }
    }
}

// ---- K2b: stream att = e~ * rv. Block (i, by): batches by*4..+3, wave each.
__global__ __launch_bounds__(256, 8) void k2b_att(
        const float* __restrict__ s1g, const float* __restrict__ s2g,
        const unsigned long long* __restrict__ adjbits,
        const float* __restrict__ rvg, float* __restrict__ att) {
    int i = blockIdx.x;
    int t = threadIdx.x, w = t >> 6, lane = t & 63;
    int b = blockIdx.y * 4 + w;
    const unsigned long long* brow = adjbits + (size_t)i * 32;
    float s1v = s1g[(size_t)b * N + i];
    float rv  = rvg[(size_t)b * N + i];
    const float* s2b = s2g + (size_t)b * N;
    float* orow = att + ((size_t)b * N + i) * N;
    #pragma unroll
    for (int it = 0; it < 8; ++it) {
        int j = it * 256 + lane * 4;
        unsigned int bits = (unsigned int)(brow[j >> 6] >> (j & 63)) & 0xFu;
        float4 sv = *(const float4*)&s2b[j];
        float x0 = s1v + sv.x; x0 = fmaxf(x0, 0.2f * x0);
        float x1 = s1v + sv.y; x1 = fmaxf(x1, 0.2f * x1);
        float x2 = s1v + sv.z; x2 = fmaxf(x2, 0.2f * x2);
        float x3 = s1v + sv.w; x3 = fmaxf(x3, 0.2f * x3);
        float4 o;
        o.x = (bits & 1u) ? __expf(x0) * rv : 0.f;
        o.y = (bits & 2u) ? __expf(x1) * rv : 0.f;
        o.z = (bits & 4u) ? __expf(x2) * rv : 0.f;
        o.w = (bits & 8u) ? __expf(x3) * rv : 0.f;
        *(float4*)&orow[j] = o;                   // 1KB/wave contiguous
    }
}

extern "C" void kernel_launch(void* const* d_in, const int* in_sizes, int n_in,
                              void* d_out, int out_size, void* d_ws, size_t ws_size,
                              hipStream_t stream) {
    const float* inp = (const float*)d_in[0];   // (8,2048,128) f32
    const int*   adj = (const int*)d_in[1];     // (2048,2048) i32
    const float* W   = (const float*)d_in[2];   // (128,64) f32
    const float* a   = (const float*)d_in[3];   // (128,1) f32

    float* out = (float*)d_out;                        // (8,2048,64)
    float* att = out + (size_t)B * N * FOUT;           // (8,2048,2048)

    unsigned short* hT = (unsigned short*)d_ws;        // 2 MB bf16 [b][o][i]
    float* s1  = (float*)(hT + (size_t)B * FOUT * N);  // 64 KB
    float* s2  = s1 + (size_t)B * N;                   // 64 KB
    float* rvg = s2 + (size_t)B * N;                   // 64 KB
    unsigned long long* adjbits = (unsigned long long*)(rvg + (size_t)B * N); // 512 KB

    kA<<<512, 512, 0, stream>>>(inp, W, a, adj, hT, s1, s2, adjbits);
    dim3 g2a(N / 64, B);
    k2a_pv<<<g2a, 1024, 0, stream>>>(s1, s2, adjbits, hT, rvg, out);
    dim3 g2b(N, 2);
    k2b_att<<<g2b, 256, 0, stream>>>(s1, s2, adjbits, rvg, att);
}